// Round 3
// baseline (212.368 us; speedup 1.0000x reference)
//
#include <hip/hip_runtime.h>
#include <hip/hip_bf16.h>

#define BATCH 32
#define LSEQ  512
#define NDIM  1024
#define NSPLIT 16

typedef __attribute__((ext_vector_type(8))) short bf16x8;
typedef __attribute__((ext_vector_type(4))) float f32x4;

__device__ __forceinline__ unsigned short f2bf(float x) {
    __hip_bfloat16 h = __float2bfloat16(x);
    return __builtin_bit_cast(unsigned short, h);
}

// ---------------------------------------------------------------------------
// Kernel 1: fused X fp32 -> bf16 conversion + s1/s2 partial sums
// grid (NSPLIT l-splits, 32 batches) x 256 threads; thread t owns n = 4t..4t+3
// ---------------------------------------------------------------------------
__global__ __launch_bounds__(256) void prep_kernel(
    const float* __restrict__ X, const float* __restrict__ W,
    unsigned short* __restrict__ Xb, float* __restrict__ P1, float* __restrict__ P2)
{
    __shared__ float sw[2 * LSEQ];
    int tid = threadIdx.x;
    for (int i = tid; i < 2 * LSEQ; i += 256) sw[i] = W[i];
    __syncthreads();

    int b  = blockIdx.y;
    int sp = blockIdx.x;
    int l0 = sp * (LSEQ / NSPLIT);
    size_t base = ((size_t)b * LSEQ + l0) * NDIM + tid * 4;
    const float* xp = X + base;
    unsigned short* xbp = Xb + base;

    float a0=0,a1=0,a2=0,a3=0, c0=0,c1=0,c2=0,c3=0;
    for (int l = 0; l < LSEQ / NSPLIT; ++l) {
        float4 x = *(const float4*)(xp + (size_t)l * NDIM);
        float w1 = sw[l0 + l], w2 = sw[LSEQ + l0 + l];
        a0 = fmaf(x.x, w1, a0); a1 = fmaf(x.y, w1, a1);
        a2 = fmaf(x.z, w1, a2); a3 = fmaf(x.w, w1, a3);
        c0 = fmaf(x.x, w2, c0); c1 = fmaf(x.y, w2, c1);
        c2 = fmaf(x.z, w2, c2); c3 = fmaf(x.w, w2, c3);
        ushort4 u; u.x = f2bf(x.x); u.y = f2bf(x.y); u.z = f2bf(x.z); u.w = f2bf(x.w);
        *(ushort4*)(xbp + (size_t)l * NDIM) = u;
    }
    size_t po = ((size_t)sp * BATCH + b) * NDIM + tid * 4;
    *(float4*)(P1 + po) = make_float4(a0, a1, a2, a3);
    *(float4*)(P2 + po) = make_float4(c0, c1, c2, c3);
}

// ---------------------------------------------------------------------------
// Kernel 2: fused reduce + softmax-denominator stats.
// No max-subtraction: e = lrelu(s1+s2) is bounded (~[-0.1, +6]), fp32 exp safe.
// Grid 256 = (b:32) x (jslice:8, 128 j each).  Each block redundantly reduces
// s1[b,:] (tiny, L2-hot partials), reduces its own s2 slice, then computes
// rd[b,j] = 1 / sum_i exp(e_ij) with the diagonal of e zeroed.
// ---------------------------------------------------------------------------
__global__ __launch_bounds__(256) void stats_kernel(
    const float* __restrict__ P1, const float* __restrict__ P2,
    float* __restrict__ s1, float* __restrict__ s2, float* __restrict__ rd)
{
    __shared__ float s1s[NDIM];
    __shared__ float s2s[128];
    int t = threadIdx.x;
    int b = blockIdx.x >> 3, sl = blockIdx.x & 7;
    int j0 = sl * 128;

    // reduce s1[b, :] (all 1024), stash in LDS; slice 0 also writes global
    #pragma unroll
    for (int q = 0; q < 4; ++q) {
        int n = q * 256 + t;
        float a = 0.f;
        #pragma unroll
        for (int sp = 0; sp < NSPLIT; ++sp)
            a += P1[((size_t)sp * BATCH + b) * NDIM + n];
        s1s[n] = a;
        if (sl == 0) s1[b * NDIM + n] = a;
    }
    // reduce s2[b, j0..j0+127]
    if (t < 128) {
        int j = j0 + t;
        float c = 0.f;
        #pragma unroll
        for (int sp = 0; sp < NSPLIT; ++sp)
            c += P2[((size_t)sp * BATCH + b) * NDIM + j];
        s2s[t] = c;
        s2[b * NDIM + j] = c;
    }
    __syncthreads();

    // thread t: j = j0 + (t>>1), half (t&1) of the i-range
    int jl = t >> 1, half = t & 1;
    int jg = j0 + jl;
    float s2j = s2s[jl];
    float sum = 0.f;
    int i0 = half * 512;
    for (int i = i0; i < i0 + 512; ++i) {
        float v = s1s[i] + s2j;
        v = fmaxf(v, 0.01f * v);          // leaky relu
        if (i == jg) v = 0.f;             // diag of e zeroed before softmax
        sum += __expf(v);
    }
    sum += __shfl_xor(sum, 1);            // combine the two halves (lane pair)
    if (half == 0) rd[b * NDIM + jg] = 1.0f / sum;
}

// ---------------------------------------------------------------------------
// Kernel 3: batched GEMM  out[b] = sigmoid( Xb[b] (512x1024) @ alpha[b]^T )
// with the alpha B-tile generated ON THE FLY each K-iter (no Bt array):
//   alpha[i=n][j=k] = exp(e) * rd[j],  e = (i==j) ? 0 : lrelu(s1[i]+s2[j])
// The alpha VALU/exp work fills the global_load_lds latency window.
// 128x128 tile, BK=32, 4 waves (2x2), 16x16x32 bf16 MFMA, sigmoid epilogue.
// XCD swizzle: xcd = flat&7 processes one batch at a time (Xb[b] = 1MB in L2).
// ---------------------------------------------------------------------------
__global__ __launch_bounds__(256) void gemm_kernel(
    const unsigned short* __restrict__ Xb,
    const float* __restrict__ s1, const float* __restrict__ s2,
    const float* __restrict__ rd, float* __restrict__ out)
{
    __shared__ __align__(16) unsigned short Xs[128 * 32];
    __shared__ __align__(16) unsigned short Bs[128 * 32];

    int tid = threadIdx.x, wid = tid >> 6, lane = tid & 63;
    int wm = wid >> 1, wn = wid & 1;

    // XCD-aware decode (HW round-robins flat block id % 8 across XCDs)
    int flat = blockIdx.x;
    int xcd   = flat & 7;
    int idx   = flat >> 3;
    int bg    = idx >> 5;
    int inner = idx & 31;
    int b  = bg * 8 + xcd;
    int n0 = (inner & 7) * 128;
    int l0 = (inner >> 3) * 128;

    const unsigned short* Xg = Xb + ((size_t)b * LSEQ + l0) * NDIM;
    const float* s2b = s2 + b * NDIM;
    const float* rdb = rd + b * NDIM;

    int rin = lane >> 2, ch = lane & 3;    // X staging: 4 lanes per 64B row

    // alpha-gen assignment: thread t -> row n = t>>1, k-half koff = (t&1)*16
    int an   = tid >> 1;
    int koff = (tid & 1) * 16;
    float s1i = s1[b * NDIM + n0 + an];    // hoisted: fixed per thread

    f32x4 acc[4][4] = {};

    for (int kb = 0; kb < 32; ++kb) {
        int k0 = kb * 32;
        __syncthreads();                   // protect LDS from prior-iter readers

        // issue async X staging first so it flies during alpha-gen
        #pragma unroll
        for (int q = 0; q < 2; ++q) {
            int row = wid * 32 + q * 16 + rin;
            const unsigned short* gx = Xg + (size_t)row * NDIM + k0 + ch * 8;
            unsigned short* lx = &Xs[(wid * 32 + q * 16) * 32];  // wave-uniform base
            __builtin_amdgcn_global_load_lds(
                (const __attribute__((address_space(1))) void*)gx,
                (__attribute__((address_space(3))) void*)lx, 16, 0, 0);
        }

        // generate 16 alphas for (n0+an, k0+koff .. +15) into Bs
        {
            int kg0 = k0 + koff;
            float sv[16], rv[16];
            #pragma unroll
            for (int q = 0; q < 4; ++q) {
                float4 s4 = *(const float4*)(s2b + kg0 + q * 4);
                float4 r4 = *(const float4*)(rdb + kg0 + q * 4);
                sv[q*4+0]=s4.x; sv[q*4+1]=s4.y; sv[q*4+2]=s4.z; sv[q*4+3]=s4.w;
                rv[q*4+0]=r4.x; rv[q*4+1]=r4.y; rv[q*4+2]=r4.z; rv[q*4+3]=r4.w;
            }
            bf16x8 v0, v1;
            #pragma unroll
            for (int k = 0; k < 16; ++k) {
                float v = s1i + sv[k];
                v = fmaxf(v, 0.01f * v);          // leaky relu
                if (n0 + an == kg0 + k) v = 0.f;  // diag of e zeroed
                float a = __expf(v) * rv[k];
                unsigned short u = f2bf(a);
                if (k < 8) v0[k] = (short)u; else v1[k - 8] = (short)u;
            }
            *(bf16x8*)&Bs[an * 32 + koff]     = v0;
            *(bf16x8*)&Bs[an * 32 + koff + 8] = v1;
        }
        __syncthreads();                   // drains vmcnt (X) + lgkm (Bs writes)

        bf16x8 av[4], bv[4];
        int rsel = lane & 15, ksel = (lane >> 4) * 8;
        #pragma unroll
        for (int mi = 0; mi < 4; ++mi)
            av[mi] = *(const bf16x8*)&Xs[(wm * 64 + mi * 16 + rsel) * 32 + ksel];
        #pragma unroll
        for (int ni = 0; ni < 4; ++ni)
            bv[ni] = *(const bf16x8*)&Bs[(wn * 64 + ni * 16 + rsel) * 32 + ksel];
        #pragma unroll
        for (int mi = 0; mi < 4; ++mi)
            #pragma unroll
            for (int ni = 0; ni < 4; ++ni)
                acc[mi][ni] = __builtin_amdgcn_mfma_f32_16x16x32_bf16(
                    av[mi], bv[ni], acc[mi][ni], 0, 0, 0);
    }

    // epilogue: C/D layout col=lane&15, row=(lane>>4)*4+reg  [m89/m91 verified]
    float* outb = out + ((size_t)b * LSEQ + l0) * NDIM + n0;
    int rq = lane >> 4, cl = lane & 15;
    #pragma unroll
    for (int mi = 0; mi < 4; ++mi)
        #pragma unroll
        for (int ni = 0; ni < 4; ++ni) {
            int col = wn * 64 + ni * 16 + cl;
            #pragma unroll
            for (int r2 = 0; r2 < 4; ++r2) {
                int row = wm * 64 + mi * 16 + rq * 4 + r2;
                float v = acc[mi][ni][r2];
                outb[(size_t)row * NDIM + col] = 1.0f / (1.0f + __expf(-v));
            }
        }
}

// ---------------------------------------------------------------------------
extern "C" void kernel_launch(void* const* d_in, const int* in_sizes, int n_in,
                              void* d_out, int out_size, void* d_ws, size_t ws_size,
                              hipStream_t stream) {
    (void)in_sizes; (void)n_in; (void)out_size; (void)ws_size;
    const float* X = (const float*)d_in[0];
    const float* W = (const float*)d_in[1];
    float* out = (float*)d_out;

    // workspace: s1|s2|rd (32K floats each) | P1|P2 (512K floats each)
    //            | Xb bf16 32MB
    float* s1 = (float*)d_ws;
    float* s2 = s1 + BATCH * NDIM;
    float* rd = s2 + BATCH * NDIM;
    float* P1 = rd + BATCH * NDIM;
    float* P2 = P1 + (size_t)NSPLIT * BATCH * NDIM;
    unsigned short* Xb = (unsigned short*)(P2 + (size_t)NSPLIT * BATCH * NDIM);

    prep_kernel<<<dim3(NSPLIT, BATCH), 256, 0, stream>>>(X, W, Xb, P1, P2);
    stats_kernel<<<256, 256, 0, stream>>>(P1, P2, s1, s2, rd);
    gemm_kernel<<<1024, 256, 0, stream>>>(Xb, s1, s2, rd, out);
}

// Round 4
// 198.239 us; speedup vs baseline: 1.0713x; 1.0713x over previous
//
#include <hip/hip_runtime.h>
#include <hip/hip_bf16.h>

#define BATCH 32
#define LSEQ  512
#define NDIM  1024
#define NSPLIT 16

typedef __attribute__((ext_vector_type(8))) short bf16x8;
typedef __attribute__((ext_vector_type(4))) float f32x4;

__device__ __forceinline__ unsigned short f2bf(float x) {
    __hip_bfloat16 h = __float2bfloat16(x);
    return __builtin_bit_cast(unsigned short, h);
}

// ---------------------------------------------------------------------------
// Kernel 1: fused X fp32 -> bf16 conversion + s1/s2 partial sums
// grid (NSPLIT l-splits, 32 batches) x 256 threads; thread t owns n = 4t..4t+3
// ---------------------------------------------------------------------------
__global__ __launch_bounds__(256) void prep_kernel(
    const float* __restrict__ X, const float* __restrict__ W,
    unsigned short* __restrict__ Xb, float* __restrict__ P1, float* __restrict__ P2)
{
    __shared__ float sw[2 * LSEQ];
    int tid = threadIdx.x;
    for (int i = tid; i < 2 * LSEQ; i += 256) sw[i] = W[i];
    __syncthreads();

    int b  = blockIdx.y;
    int sp = blockIdx.x;
    int l0 = sp * (LSEQ / NSPLIT);
    size_t base = ((size_t)b * LSEQ + l0) * NDIM + tid * 4;
    const float* xp = X + base;
    unsigned short* xbp = Xb + base;

    float a0=0,a1=0,a2=0,a3=0, c0=0,c1=0,c2=0,c3=0;
    for (int l = 0; l < LSEQ / NSPLIT; ++l) {
        float4 x = *(const float4*)(xp + (size_t)l * NDIM);
        float w1 = sw[l0 + l], w2 = sw[LSEQ + l0 + l];
        a0 = fmaf(x.x, w1, a0); a1 = fmaf(x.y, w1, a1);
        a2 = fmaf(x.z, w1, a2); a3 = fmaf(x.w, w1, a3);
        c0 = fmaf(x.x, w2, c0); c1 = fmaf(x.y, w2, c1);
        c2 = fmaf(x.z, w2, c2); c3 = fmaf(x.w, w2, c3);
        ushort4 u; u.x = f2bf(x.x); u.y = f2bf(x.y); u.z = f2bf(x.z); u.w = f2bf(x.w);
        *(ushort4*)(xbp + (size_t)l * NDIM) = u;
    }
    size_t po = ((size_t)sp * BATCH + b) * NDIM + tid * 4;
    *(float4*)(P1 + po) = make_float4(a0, a1, a2, a3);
    *(float4*)(P2 + po) = make_float4(c0, c1, c2, c3);
}

// ---------------------------------------------------------------------------
// Kernel 2: fused reduce + softmax-denominator stats (no max-subtraction;
// e = lrelu(s1+s2) is bounded, fp32 exp safe — validated R3, absmax 3.9e-3).
// Grid 256 = (b:32) x (jslice:8, 128 j each).
// ---------------------------------------------------------------------------
__global__ __launch_bounds__(256) void stats_kernel(
    const float* __restrict__ P1, const float* __restrict__ P2,
    float* __restrict__ s1, float* __restrict__ s2, float* __restrict__ rd)
{
    __shared__ float s1s[NDIM];
    __shared__ float s2s[128];
    int t = threadIdx.x;
    int b = blockIdx.x >> 3, sl = blockIdx.x & 7;
    int j0 = sl * 128;

    #pragma unroll
    for (int q = 0; q < 4; ++q) {
        int n = q * 256 + t;
        float a = 0.f;
        #pragma unroll
        for (int sp = 0; sp < NSPLIT; ++sp)
            a += P1[((size_t)sp * BATCH + b) * NDIM + n];
        s1s[n] = a;
        if (sl == 0) s1[b * NDIM + n] = a;
    }
    if (t < 128) {
        int j = j0 + t;
        float c = 0.f;
        #pragma unroll
        for (int sp = 0; sp < NSPLIT; ++sp)
            c += P2[((size_t)sp * BATCH + b) * NDIM + j];
        s2s[t] = c;
        s2[b * NDIM + j] = c;
    }
    __syncthreads();

    int jl = t >> 1, half = t & 1;
    int jg = j0 + jl;
    float s2j = s2s[jl];
    float sum = 0.f;
    int i0 = half * 512;
    for (int i = i0; i < i0 + 512; ++i) {
        float v = s1s[i] + s2j;
        v = fmaxf(v, 0.01f * v);          // leaky relu
        if (i == jg) v = 0.f;             // diag of e zeroed before softmax
        sum += __expf(v);
    }
    sum += __shfl_xor(sum, 1);
    if (half == 0) rd[b * NDIM + jg] = 1.0f / sum;
}

// ---------------------------------------------------------------------------
// Kernel 3: Bt[b][i][j] = exp(e_ij) * rd[b,j] in bf16 (GEMM B-operand [n][k]).
// One wave per (b,i); lane owns 8 contiguous j per pass, 2 passes; 16B stores.
// ---------------------------------------------------------------------------
__global__ __launch_bounds__(256) void btgen_kernel(
    const float* __restrict__ s1, const float* __restrict__ s2,
    const float* __restrict__ rd, unsigned short* __restrict__ Bt)
{
    int wid = threadIdx.x >> 6, lane = threadIdx.x & 63;
    int r = blockIdx.x * 4 + wid;          // (b,i) flat
    int b = r >> 10, i = r & 1023;
    float s1i = s1[r];
    const float* s2b = s2 + b * NDIM;
    const float* rdb = rd + b * NDIM;
    unsigned short* outp = Bt + (size_t)r * NDIM;

    #pragma unroll
    for (int q = 0; q < 2; ++q) {
        int j0 = q * 512 + lane * 8;
        float sv[8], rv[8];
        #pragma unroll
        for (int h = 0; h < 2; ++h) {
            float4 s4 = *(const float4*)(s2b + j0 + h * 4);
            float4 r4 = *(const float4*)(rdb + j0 + h * 4);
            sv[h*4+0]=s4.x; sv[h*4+1]=s4.y; sv[h*4+2]=s4.z; sv[h*4+3]=s4.w;
            rv[h*4+0]=r4.x; rv[h*4+1]=r4.y; rv[h*4+2]=r4.z; rv[h*4+3]=r4.w;
        }
        bf16x8 v;
        #pragma unroll
        for (int k = 0; k < 8; ++k) {
            float e = s1i + sv[k];
            e = fmaxf(e, 0.01f * e);       // leaky relu
            if (j0 + k == i) e = 0.f;      // diag of e zeroed (alpha nonzero there)
            v[k] = (short)f2bf(__expf(e) * rv[k]);
        }
        *(bf16x8*)&outp[j0] = v;
    }
}

// ---------------------------------------------------------------------------
// Kernel 4: batched GEMM  out[b] = sigmoid( Xb[b] (512x1024) @ Bt[b]^T )
// 128x128 tile, BK=64 stored as two k-halves [kh][128][32] (keeps the
// conflict-benign [row][32] LDS pattern AND global_load_lds contiguity),
// 16 K-iters (half the barrier round-trips of BK=32), 4 waves (2x2),
// 16x16x32 bf16 MFMA x32/wave/iter, sigmoid epilogue.
// XCD swizzle: xcd = flat&7 processes one batch at a time (L2-resident).
// ---------------------------------------------------------------------------
__global__ __launch_bounds__(256) void gemm_kernel(
    const unsigned short* __restrict__ Xb, const unsigned short* __restrict__ Bt,
    float* __restrict__ out)
{
    __shared__ __align__(16) unsigned short Xs[2 * 128 * 32];  // [kh][row][32]
    __shared__ __align__(16) unsigned short Bs[2 * 128 * 32];

    int tid = threadIdx.x, wid = tid >> 6, lane = tid & 63;
    int wm = wid >> 1, wn = wid & 1;

    int flat = blockIdx.x;
    int xcd   = flat & 7;
    int idx   = flat >> 3;
    int bg    = idx >> 5;
    int inner = idx & 31;
    int b  = bg * 8 + xcd;
    int n0 = (inner & 7) * 128;
    int l0 = (inner >> 3) * 128;

    const unsigned short* Xg = Xb + ((size_t)b * LSEQ + l0) * NDIM;
    const unsigned short* Bg = Bt + ((size_t)b * NDIM + n0) * NDIM;

    int rin = lane >> 2, ch = lane & 3;    // staging: 4 lanes per 64B row-half

    f32x4 acc[4][4] = {};

    for (int kb = 0; kb < 16; ++kb) {
        int k0 = kb * 64;
        __syncthreads();                   // protect LDS from prior-iter readers
        #pragma unroll
        for (int kh = 0; kh < 2; ++kh) {
            #pragma unroll
            for (int q = 0; q < 2; ++q) {
                int row = wid * 32 + q * 16 + rin;
                int kg = k0 + kh * 32 + ch * 8;
                const unsigned short* gx = Xg + (size_t)row * NDIM + kg;
                const unsigned short* gb = Bg + (size_t)row * NDIM + kg;
                unsigned short* lx = &Xs[kh * 4096 + (wid * 32 + q * 16) * 32];
                unsigned short* lb = &Bs[kh * 4096 + (wid * 32 + q * 16) * 32];
                __builtin_amdgcn_global_load_lds(
                    (const __attribute__((address_space(1))) void*)gx,
                    (__attribute__((address_space(3))) void*)lx, 16, 0, 0);
                __builtin_amdgcn_global_load_lds(
                    (const __attribute__((address_space(1))) void*)gb,
                    (__attribute__((address_space(3))) void*)lb, 16, 0, 0);
            }
        }
        __syncthreads();

        int rsel = lane & 15, ksel = (lane >> 4) * 8;
        #pragma unroll
        for (int kh = 0; kh < 2; ++kh) {
            bf16x8 av[4], bv[4];
            #pragma unroll
            for (int mi = 0; mi < 4; ++mi)
                av[mi] = *(const bf16x8*)&Xs[kh * 4096 + (wm * 64 + mi * 16 + rsel) * 32 + ksel];
            #pragma unroll
            for (int ni = 0; ni < 4; ++ni)
                bv[ni] = *(const bf16x8*)&Bs[kh * 4096 + (wn * 64 + ni * 16 + rsel) * 32 + ksel];
            #pragma unroll
            for (int mi = 0; mi < 4; ++mi)
                #pragma unroll
                for (int ni = 0; ni < 4; ++ni)
                    acc[mi][ni] = __builtin_amdgcn_mfma_f32_16x16x32_bf16(
                        av[mi], bv[ni], acc[mi][ni], 0, 0, 0);
        }
    }

    // epilogue: C/D layout col=lane&15, row=(lane>>4)*4+reg  [m89/m91 verified]
    float* outb = out + ((size_t)b * LSEQ + l0) * NDIM + n0;
    int rq = lane >> 4, cl = lane & 15;
    #pragma unroll
    for (int mi = 0; mi < 4; ++mi)
        #pragma unroll
        for (int ni = 0; ni < 4; ++ni) {
            int col = wn * 64 + ni * 16 + cl;
            #pragma unroll
            for (int r2 = 0; r2 < 4; ++r2) {
                int row = wm * 64 + mi * 16 + rq * 4 + r2;
                float v = acc[mi][ni][r2];
                outb[(size_t)row * NDIM + col] = 1.0f / (1.0f + __expf(-v));
            }
        }
}

// ---------------------------------------------------------------------------
extern "C" void kernel_launch(void* const* d_in, const int* in_sizes, int n_in,
                              void* d_out, int out_size, void* d_ws, size_t ws_size,
                              hipStream_t stream) {
    (void)in_sizes; (void)n_in; (void)out_size; (void)ws_size;
    const float* X = (const float*)d_in[0];
    const float* W = (const float*)d_in[1];
    float* out = (float*)d_out;

    // workspace: s1|s2|rd (32K floats each) | P1|P2 (512K floats each)
    //            | Xb bf16 32MB | Bt bf16 64MB   (~100.4 MB, same as R2)
    float* s1 = (float*)d_ws;
    float* s2 = s1 + BATCH * NDIM;
    float* rd = s2 + BATCH * NDIM;
    float* P1 = rd + BATCH * NDIM;
    float* P2 = P1 + (size_t)NSPLIT * BATCH * NDIM;
    unsigned short* Xb = (unsigned short*)(P2 + (size_t)NSPLIT * BATCH * NDIM);
    unsigned short* Bt = Xb + (size_t)BATCH * LSEQ * NDIM;

    prep_kernel<<<dim3(NSPLIT, BATCH), 256, 0, stream>>>(X, W, Xb, P1, P2);
    stats_kernel<<<256, 256, 0, stream>>>(P1, P2, s1, s2, rd);
    btgen_kernel<<<(BATCH * NDIM) / 4, 256, 0, stream>>>(s1, s2, rd, Bt);
    gemm_kernel<<<1024, 256, 0, stream>>>(Xb, Bt, out);
}